// Round 7
// baseline (180.363 us; speedup 1.0000x reference)
//
#include <hip/hip_runtime.h>
#include <math.h>

#define BB 64
#define QQ 600
#define NT 80
#define NC 92
#define SLOTS 10     // ceil(600/64)
#define NTILE 10     // 64-query tiles per batch
#define MAXROUNDS 48 // auction round cap before draining to Dijkstra

// ---------------------------------------------------------------------------
// Single fused kernel: block = one batch.
// Phase A: cost matrix (10 tiles, 4 waves) + per-row (min,2nd-min,argmin).
// Phase B: Jacobi parallel auction (v<=0 invariant -> rectangular-dual valid).
// Phase C: Dijkstra SAP drain (wave 0; exact from any feasible dual state).
// ---------------------------------------------------------------------------
__global__ __launch_bounds__(256) void matcher_kernel(
    const float* __restrict__ logits,   // (B,Q,NC)
    const float* __restrict__ pboxes,   // (B,Q,4)
    const int*   __restrict__ tlabels,  // (B,NT)
    const float* __restrict__ tboxes,   // (B,NT,4)
    float* __restrict__ cost,           // (B,NT,QQ) workspace
    int* __restrict__ rows_out,         // (B,NT)
    int* __restrict__ cols_out)         // (B,NT)
{
    __shared__ float  tile[64 * 93];    // logits tile; exp() stored in place
    __shared__ float  s_pm[4 * 64], s_ps[4 * 64];
    __shared__ float  s_m[64], s_s[64];
    __shared__ float  s_tb[NT * 4];
    __shared__ int    s_tl[NT];
    // solver state
    __shared__ double vA[QQ];
    __shared__ double u[NT];
    __shared__ double bidm1[NT], bidm2[NT];
    __shared__ int    bidj[NT], bidver[NT];
    __shared__ int    pA[QQ];
    __shared__ int    verA[QQ];
    __shared__ int    colrow[QQ];
    __shared__ int    assigned[NT];
    __shared__ int    plist[NT];
    __shared__ int    pcnt;
    __shared__ int    wayA[QQ];
    __shared__ int    c4r[NT];
    __shared__ int    djkA[NT];

    const int b    = blockIdx.x;
    const int tid  = threadIdx.x;
    const int qq   = tid & 63;          // lane within wave
    const int wv   = tid >> 6;          // wave id (0..3)
    const float* C = cost + (size_t)b * NT * QQ;

    // init solver state (no overlap with Phase A's tile buffers)
    for (int c = tid; c < QQ; c += 256) { pA[c] = -1; verA[c] = 0; vA[c] = 0.0; }
    if (tid < NT) { assigned[tid] = 0; bidver[tid] = 0; }
    for (int i = tid; i < NT * 4; i += 256) s_tb[i] = tboxes[b * NT * 4 + i];
    for (int i = tid; i < NT;     i += 256) s_tl[i] = tlabels[b * NT + i];

    // ================= Phase A: cost tiles + row-min partials ==============
    float rm1[20], rm2[20]; int rj[20];
    #pragma unroll
    for (int tt = 0; tt < 20; ++tt) { rm1[tt] = INFINITY; rm2[tt] = INFINITY; rj[tt] = QQ; }

    for (int tix = 0; tix < NTILE; ++tix) {
        const int q0 = tix * 64;
        const int nq = min(64, QQ - q0);      // 24 on the last tile
        __syncthreads();                      // tile reuse protection
        const float* src = logits + ((size_t)b * QQ + q0) * NC;
        for (int idx = tid; idx < nq * NC; idx += 256) {
            const int r = idx / NC;
            tile[r * 93 + (idx - r * NC)] = src[idx];
        }
        __syncthreads();
        // softmax stats: wave wv covers classes [wv*23, wv*23+23)
        if (qq < nq) {
            const float* r = &tile[qq * 93];
            float pm = -INFINITY;
            for (int c = wv * 23; c < wv * 23 + 23; ++c) pm = fmaxf(pm, r[c]);
            s_pm[wv * 64 + qq] = pm;
        }
        __syncthreads();
        if (tid < nq)
            s_m[tid] = fmaxf(fmaxf(s_pm[tid], s_pm[64 + tid]),
                             fmaxf(s_pm[128 + tid], s_pm[192 + tid]));
        __syncthreads();
        if (qq < nq) {
            const float m = s_m[qq];
            float* r = &tile[qq * 93];
            float ps = 0.f;
            for (int c = wv * 23; c < wv * 23 + 23; ++c) {
                const float e = expf(r[c] - m);
                r[c] = e;                     // store prob numerator in place
                ps += e;
            }
            s_ps[wv * 64 + qq] = ps;
        }
        __syncthreads();
        if (tid < nq)
            s_s[tid] = (s_ps[tid] + s_ps[64 + tid]) + (s_ps[128 + tid] + s_ps[192 + tid]);
        __syncthreads();

        // cost for this wave's 20 targets over 64 queries
        const int q = q0 + qq;
        float px1 = 0.f, py1 = 0.f, px2 = 0.f, py2 = 0.f, pa = 0.f, s = 1.f;
        if (qq < nq) {
            const float* pb = pboxes + ((size_t)b * QQ + q) * 4;
            px1 = pb[0]; py1 = pb[1]; px2 = pb[2]; py2 = pb[3];
            pa  = (px2 - px1) * (py2 - py1);
            s   = s_s[qq];
        }
        float* crow = cost + (size_t)b * NT * QQ + q;
        #pragma unroll
        for (int tt = 0; tt < 20; ++tt) {
            const int t = wv * 20 + tt;
            float costv = INFINITY;
            if (qq < nq) {
                const int lbl = s_tl[t];
                const float cc = -(tile[qq * 93 + lbl] / s);  // == -exp(x-m)/s
                const float tx1 = s_tb[t*4+0], ty1 = s_tb[t*4+1];
                const float tx2 = s_tb[t*4+2], ty2 = s_tb[t*4+3];
                const float cb = fabsf(px1-tx1) + fabsf(py1-ty1)
                               + fabsf(px2-tx2) + fabsf(py2-ty2);
                const float ta = (tx2 - tx1) * (ty2 - ty1);
                const float iw = fmaxf(fminf(px2, tx2) - fmaxf(px1, tx1), 0.f);
                const float ih = fmaxf(fminf(py2, ty2) - fmaxf(py1, ty1), 0.f);
                const float inter = iw * ih;
                const float uni   = pa + ta - inter;
                const float iou   = inter / uni;
                const float cw = fmaxf(fmaxf(px2, tx2) - fminf(px1, tx1), 0.f);
                const float ch = fmaxf(fmaxf(py2, ty2) - fminf(py1, ty1), 0.f);
                const float ac = cw * ch;
                const float giou = iou - (ac - uni) / ac;
                costv = (1.0f * cc + 5.0f * cb) + 2.0f * (-giou);
                crow[(size_t)t * QQ] = costv;
            }
            // running per-thread (min, 2nd-min, argmin); q ascends with tix
            if (costv < rm1[tt]) { rm2[tt] = rm1[tt]; rm1[tt] = costv; rj[tt] = q; }
            else                 { rm2[tt] = fminf(rm2[tt], costv); }
        }
    }
    // final butterflies: one per target
    #pragma unroll
    for (int tt = 0; tt < 20; ++tt) {
        const int t = wv * 20 + tt;
        float b1 = rm1[tt], b2 = rm2[tt]; int bj = rj[tt];
        #pragma unroll
        for (int off = 32; off > 0; off >>= 1) {
            const float o1 = __shfl_xor(b1, off);
            const float o2 = __shfl_xor(b2, off);
            const int   oj = __shfl_xor(bj, off);
            if (o1 < b1 || (o1 == b1 && oj < bj)) {
                b2 = fminf(b1, o2); b1 = o1; bj = oj;
            } else {
                b2 = fminf(o1, b2);
            }
        }
        if (qq == 0) {
            bidm1[t] = (double)b1; bidm2[t] = (double)b2; bidj[t] = bj;
            u[t] = (double)b1;     // feasible: keys only increase afterwards
        }
    }
    __syncthreads();

    // ================= Phase B: Jacobi parallel auction ====================
    // Invariants: v <= 0 and only decreases; accepted bids are version-fresh
    // => tight & feasible (each acceptance == one legal Gauss-Seidel step;
    // distinct columns => parallel acceptances commute).
    for (int round = 0; round < MAXROUNDS; ++round) {
        for (int c = tid; c < QQ; c += 256) colrow[c] = 0x7fffffff;
        if (tid == 0) pcnt = 0;
        __syncthreads();
        // post (winner = min row index among version-fresh bidders)
        if (tid < NT && !assigned[tid]) {
            const int j = bidj[tid];
            if (bidver[tid] == verA[j]) atomicMin(&colrow[j], tid);
        }
        __syncthreads();
        // accept (disjoint columns -> race-free)
        if (tid < NT && !assigned[tid]) {
            const int i = tid, j = bidj[i];
            if (bidver[i] == verA[j] && colrow[j] == i) {
                const double m1 = bidm1[i], m2 = bidm2[i];
                const int prev = pA[j];
                pA[j] = i;
                verA[j] = verA[j] + 1;
                vA[j] -= (m2 - m1);          // v only decreases (>=0 diff)
                u[i] = m2;
                assigned[i] = 1;
                if (prev >= 0) assigned[prev] = 0;   // displaced -> re-bid
            }
        }
        __syncthreads();
        if (tid < NT && !assigned[tid]) { const int k = atomicAdd(&pcnt, 1); plist[k] = tid; }
        __syncthreads();
        const int np = pcnt;
        if (np == 0) break;
        // re-bid pending rows in parallel: wave wv takes plist[wv], [wv+4], ...
        for (int idx = wv; idx < np; idx += 4) {
            const int i = plist[idx];
            const float* rp = C + (size_t)i * QQ;
            float rowv[SLOTS];
            #pragma unroll
            for (int k = 0; k < SLOTS; ++k) { const int c = qq + 64*k; rowv[k] = (c < QQ) ? rp[c] : 0.f; }
            double m1 = INFINITY, m2 = INFINITY; int j1 = QQ;
            #pragma unroll
            for (int k = 0; k < SLOTS; ++k) {
                const int c = qq + 64 * k;
                if (c < QQ) {
                    const double key = (double)rowv[k] - vA[c];
                    if (key < m1)      { m2 = m1; m1 = key; j1 = c; }
                    else if (key < m2) { m2 = key; }
                }
            }
            #pragma unroll
            for (int off = 32; off > 0; off >>= 1) {
                const double om1 = __shfl_xor(m1, off);
                const int    oj1 = __shfl_xor(j1, off);
                const double om2 = __shfl_xor(m2, off);
                if (om1 < m1 || (om1 == m1 && oj1 < j1)) {
                    m2 = fmin(m1, om2); m1 = om1; j1 = oj1;
                } else {
                    m2 = fmin(om1, m2);
                }
            }
            if (qq == 0) {
                bidm1[i] = m1; bidm2[i] = m2; bidj[i] = j1;
                bidver[i] = verA[j1];
                u[i] = m1;                   // feasible forever (v only dec.)
            }
        }
        __syncthreads();
    }

    if (wv != 0) return;   // ============ wave 0 only below; no barriers ====
    const int lane = qq;

    // collect drained rows (uniform control flow)
    int nd = 0;
    for (int i = 0; i < NT; ++i) {
        if (!assigned[i]) { if (lane == 0) djkA[nd] = i; ++nd; }
    }

    // load duals/assignment into registers
    double v_[SLOTS], minv_[SLOTS];
    int p_[SLOTS];
    #pragma unroll
    for (int k = 0; k < SLOTS; ++k) {
        const int c = lane + 64 * k;
        v_[k] = (c < QQ) ? vA[c] : 0.0;
        p_[k] = (c < QQ) ? pA[c] : -1;
    }

    // ================= Phase C: Dijkstra SAP (exact, verified R2-R6) =======
    float rowv[SLOTS];
    for (int ii = 0; ii < nd; ++ii) {
        const int i = djkA[ii];
        #pragma unroll
        for (int k = 0; k < SLOTS; ++k) minv_[k] = INFINITY;
        unsigned usedm = 0;
        int j0 = -1;
        double ui0 = u[i];
        {
            const float* rp = C + (size_t)i * QQ;
            #pragma unroll
            for (int k = 0; k < SLOTS; ++k) { const int c = lane + 64*k; rowv[k] = (c < QQ) ? rp[c] : 0.f; }
        }
        int j1, i1;

        for (;;) {
            if (j0 >= 0 && (j0 & 63) == lane) usedm |= 1u << (j0 >> 6);

            double bestv = INFINITY; int bestc = QQ;
            #pragma unroll
            for (int k = 0; k < SLOTS; ++k) {
                const int c = lane + 64 * k;
                if (c < QQ && !((usedm >> k) & 1u)) {
                    const double cur = ((double)rowv[k] - ui0) - v_[k];
                    if (cur < minv_[k]) { minv_[k] = cur; wayA[c] = j0; }
                    if (minv_[k] < bestv) { bestv = minv_[k]; bestc = c; }
                }
            }
            #pragma unroll
            for (int off = 32; off > 0; off >>= 1) {
                const double ov = __shfl_xor(bestv, off);
                const int    oc = __shfl_xor(bestc, off);
                if (ov < bestv || (ov == bestv && oc < bestc)) { bestv = ov; bestc = oc; }
            }
            const double delta = bestv;
            j1 = bestc;

            {   // i1 = p[j1] via register select + shuffle
                const int slot = j1 >> 6, lj = j1 & 63;
                int myp = p_[0];
                #pragma unroll
                for (int k = 1; k < SLOTS; ++k) if (slot == k) myp = p_[k];
                i1 = __shfl(myp, lj);
            }

            double ui_next = 0.0;
            float rown[SLOTS];
            if (i1 >= 0) {      // prefetch next row (not in tree -> u stable)
                ui_next = u[i1];
                const float* rp = C + (size_t)i1 * QQ;
                #pragma unroll
                for (int k = 0; k < SLOTS; ++k) { const int c = lane + 64*k; rown[k] = (c < QQ) ? rp[c] : 0.f; }
            }

            #pragma unroll
            for (int k = 0; k < SLOTS; ++k) {
                const int c = lane + 64 * k;
                if (c < QQ) {
                    if ((usedm >> k) & 1u) { v_[k] -= delta; u[p_[k]] += delta; }
                    else                     minv_[k] -= delta;
                }
            }
            if (lane == 0) u[i] += delta;

            j0 = j1;
            if (i1 < 0) break;
            ui0 = ui_next;
            #pragma unroll
            for (int k = 0; k < SLOTS; ++k) rowv[k] = rown[k];
        }

        if (lane == 0) {        // augment along way chain
            int jj = j1;
            while (jj >= 0) {
                const int pr = wayA[jj];
                pA[jj] = (pr < 0) ? i : pA[pr];
                jj = pr;
            }
        }
        #pragma unroll
        for (int k = 0; k < SLOTS; ++k) {
            const int c = lane + 64 * k;
            p_[k] = (c < QQ) ? pA[c] : -1;
        }
    }

    // ---- emit in increasing query order (== reference's stable argsort) ----
    #pragma unroll
    for (int k = 0; k < SLOTS; ++k) {
        const int c = lane + 64 * k;
        if (c < QQ) { const int t = pA[c]; if (t >= 0) c4r[t] = c; }
    }
    for (int t = lane; t < NT; t += 64) {
        const int c = c4r[t];
        int rank = 0;
        for (int t2 = 0; t2 < NT; ++t2) rank += (c4r[t2] < c) ? 1 : 0;
        rows_out[b * NT + rank] = c;
        cols_out[b * NT + rank] = t;
    }
}

extern "C" void kernel_launch(void* const* d_in, const int* in_sizes, int n_in,
                              void* d_out, int out_size, void* d_ws, size_t ws_size,
                              hipStream_t stream) {
    (void)in_sizes; (void)n_in; (void)out_size; (void)ws_size;
    const float* logits  = (const float*)d_in[0];
    const float* pboxes  = (const float*)d_in[1];
    const int*   tlabels = (const int*)d_in[2];
    const float* tboxes  = (const float*)d_in[3];
    float* cost = (float*)d_ws;               // (B,NT,QQ) f32 = 12.3 MB
    int*   out  = (int*)d_out;

    matcher_kernel<<<dim3(BB), 256, 0, stream>>>(
        logits, pboxes, tlabels, tboxes, cost, out, out + BB * NT);
}

// Round 8
// 151.300 us; speedup vs baseline: 1.1921x; 1.1921x over previous
//
#include <hip/hip_runtime.h>
#include <math.h>

#define BB 64
#define QQ 600
#define NT 80
#define NC 92
#define SLOTS 10     // ceil(600/64)
#define NTILE 10     // 64-query tiles per batch
#define NWAVE 16     // waves per block
#define TPW 5        // targets per wave (16*5 = 80)
#define CPW 6        // softmax classes per wave (16*6 >= 92)
#define MAXROUNDS 48 // auction round cap before draining to Dijkstra

// ---------------------------------------------------------------------------
// Single fused kernel: block = one batch, 1024 threads (16 waves).
// Phase A: cost matrix (10 tile-steps; wave w owns targets w*5..w*5+4)
//          + per-row (min, 2nd-min, argmin) bids.
// Phase B: Jacobi parallel auction (v<=0 invariant -> rectangular-dual valid).
// Phase C: Dijkstra SAP drain (wave 0; exact from any feasible dual state).
// ---------------------------------------------------------------------------
__global__ __launch_bounds__(1024) void matcher_kernel(
    const float* __restrict__ logits,   // (B,Q,NC)
    const float* __restrict__ pboxes,   // (B,Q,4)
    const int*   __restrict__ tlabels,  // (B,NT)
    const float* __restrict__ tboxes,   // (B,NT,4)
    float* __restrict__ cost,           // (B,NT,QQ) workspace
    int* __restrict__ rows_out,         // (B,NT)
    int* __restrict__ cols_out)         // (B,NT)
{
    __shared__ float  tile[64 * 93];    // logits tile; exp() stored in place
    __shared__ float  s_pm[NWAVE * 64], s_ps[NWAVE * 64];
    __shared__ float  s_m[64], s_s[64];
    __shared__ float  s_tb[NT * 4];
    __shared__ int    s_tl[NT];
    // solver state
    __shared__ double vA[QQ];
    __shared__ double u[NT];
    __shared__ double bidm1[NT], bidm2[NT];
    __shared__ int    bidj[NT], bidver[NT];
    __shared__ int    pA[QQ];
    __shared__ int    verA[QQ];
    __shared__ int    colrow[QQ];
    __shared__ int    assigned[NT];
    __shared__ int    plist[NT];
    __shared__ int    pcnt;
    __shared__ int    wayA[QQ];
    __shared__ int    c4r[NT];
    __shared__ int    djkA[NT];

    const int b    = blockIdx.x;
    const int tid  = threadIdx.x;
    const int qq   = tid & 63;          // lane within wave
    const int wv   = tid >> 6;          // wave id (0..15)
    const float* C = cost + (size_t)b * NT * QQ;

    // init solver state
    for (int c = tid; c < QQ; c += 1024) { pA[c] = -1; verA[c] = 0; vA[c] = 0.0; }
    if (tid < NT) { assigned[tid] = 0; bidver[tid] = 0; }
    for (int i = tid; i < NT * 4; i += 1024) s_tb[i] = tboxes[b * NT * 4 + i];
    for (int i = tid; i < NT;     i += 1024) s_tl[i] = tlabels[b * NT + i];

    // ================= Phase A: cost tiles + row-min bids ==================
    float rm1[TPW], rm2[TPW]; int rj[TPW];
    #pragma unroll
    for (int tt = 0; tt < TPW; ++tt) { rm1[tt] = INFINITY; rm2[tt] = INFINITY; rj[tt] = QQ; }

    const int c0 = wv * CPW;
    const int c1 = min(NC, c0 + CPW);

    for (int tix = 0; tix < NTILE; ++tix) {
        const int q0 = tix * 64;
        const int nq = min(64, QQ - q0);      // 24 on the last tile
        __syncthreads();                      // protect tile reuse
        const float* src = logits + ((size_t)b * QQ + q0) * NC;
        for (int idx = tid; idx < nq * NC; idx += 1024) {
            const int r = idx / NC;
            tile[r * 93 + (idx - r * NC)] = src[idx];
        }
        __syncthreads();
        // softmax max partials: wave wv covers classes [c0, c1)
        if (qq < nq) {
            const float* r = &tile[qq * 93];
            float pm = -INFINITY;
            for (int c = c0; c < c1; ++c) pm = fmaxf(pm, r[c]);
            s_pm[wv * 64 + qq] = pm;
        }
        __syncthreads();
        if (tid < nq) {
            float m = s_pm[tid];
            for (int w = 1; w < NWAVE; ++w) m = fmaxf(m, s_pm[w * 64 + tid]);
            s_m[tid] = m;
        }
        __syncthreads();
        if (qq < nq) {
            const float m = s_m[qq];
            float* r = &tile[qq * 93];
            float ps = 0.f;
            for (int c = c0; c < c1; ++c) {
                const float e = expf(r[c] - m);
                r[c] = e;                     // store prob numerator in place
                ps += e;
            }
            s_ps[wv * 64 + qq] = ps;
        }
        __syncthreads();
        if (tid < nq) {
            float s = 0.f;
            for (int w = 0; w < NWAVE; ++w) s += s_ps[w * 64 + tid];
            s_s[tid] = s;
        }
        __syncthreads();

        // cost for this wave's TPW targets over the 64-query tile
        const int q = q0 + qq;
        float px1 = 0.f, py1 = 0.f, px2 = 0.f, py2 = 0.f, pa = 0.f, s = 1.f;
        if (qq < nq) {
            const float* pb = pboxes + ((size_t)b * QQ + q) * 4;
            px1 = pb[0]; py1 = pb[1]; px2 = pb[2]; py2 = pb[3];
            pa  = (px2 - px1) * (py2 - py1);
            s   = s_s[qq];
        }
        float* crow = cost + (size_t)b * NT * QQ + q;
        #pragma unroll
        for (int tt = 0; tt < TPW; ++tt) {
            const int t = wv * TPW + tt;
            float costv = INFINITY;
            if (qq < nq) {
                const int lbl = s_tl[t];
                const float cc = -(tile[qq * 93 + lbl] / s);  // == -exp(x-m)/s
                const float tx1 = s_tb[t*4+0], ty1 = s_tb[t*4+1];
                const float tx2 = s_tb[t*4+2], ty2 = s_tb[t*4+3];
                const float cb = fabsf(px1-tx1) + fabsf(py1-ty1)
                               + fabsf(px2-tx2) + fabsf(py2-ty2);
                const float ta = (tx2 - tx1) * (ty2 - ty1);
                const float iw = fmaxf(fminf(px2, tx2) - fmaxf(px1, tx1), 0.f);
                const float ih = fmaxf(fminf(py2, ty2) - fmaxf(py1, ty1), 0.f);
                const float inter = iw * ih;
                const float uni   = pa + ta - inter;
                const float iou   = inter / uni;
                const float cw = fmaxf(fmaxf(px2, tx2) - fminf(px1, tx1), 0.f);
                const float ch = fmaxf(fmaxf(py2, ty2) - fminf(py1, ty1), 0.f);
                const float ac = cw * ch;
                const float giou = iou - (ac - uni) / ac;
                costv = (1.0f * cc + 5.0f * cb) + 2.0f * (-giou);
                crow[(size_t)t * QQ] = costv;
            }
            // running per-thread (min, 2nd-min, argmin); q ascends with tix
            if (costv < rm1[tt]) { rm2[tt] = rm1[tt]; rm1[tt] = costv; rj[tt] = q; }
            else                 { rm2[tt] = fminf(rm2[tt], costv); }
        }
    }
    // final butterflies: one per owned target
    #pragma unroll
    for (int tt = 0; tt < TPW; ++tt) {
        const int t = wv * TPW + tt;
        float b1 = rm1[tt], b2 = rm2[tt]; int bj = rj[tt];
        #pragma unroll
        for (int off = 32; off > 0; off >>= 1) {
            const float o1 = __shfl_xor(b1, off);
            const float o2 = __shfl_xor(b2, off);
            const int   oj = __shfl_xor(bj, off);
            if (o1 < b1 || (o1 == b1 && oj < bj)) {
                b2 = fminf(b1, o2); b1 = o1; bj = oj;
            } else {
                b2 = fminf(o1, b2);
            }
        }
        if (qq == 0) {
            bidm1[t] = (double)b1; bidm2[t] = (double)b2; bidj[t] = bj;
            u[t] = (double)b1;     // feasible: keys only increase afterwards
        }
    }
    __syncthreads();

    // ================= Phase B: Jacobi parallel auction ====================
    // Invariants: v <= 0 and only decreases; accepted bids are version-fresh
    // => tight & feasible (each acceptance == one legal Gauss-Seidel step;
    // distinct columns => parallel acceptances commute). Verified R7.
    for (int round = 0; round < MAXROUNDS; ++round) {
        for (int c = tid; c < QQ; c += 1024) colrow[c] = 0x7fffffff;
        if (tid == 0) pcnt = 0;
        __syncthreads();
        // post (winner = min row index among version-fresh bidders)
        if (tid < NT && !assigned[tid]) {
            const int j = bidj[tid];
            if (bidver[tid] == verA[j]) atomicMin(&colrow[j], tid);
        }
        __syncthreads();
        // accept (disjoint columns -> race-free)
        if (tid < NT && !assigned[tid]) {
            const int i = tid, j = bidj[i];
            if (bidver[i] == verA[j] && colrow[j] == i) {
                const double m1 = bidm1[i], m2 = bidm2[i];
                const int prev = pA[j];
                pA[j] = i;
                verA[j] = verA[j] + 1;
                vA[j] -= (m2 - m1);          // v only decreases (>=0 diff)
                u[i] = m2;
                assigned[i] = 1;
                if (prev >= 0) assigned[prev] = 0;   // displaced -> re-bid
            }
        }
        __syncthreads();
        if (tid < NT && !assigned[tid]) { const int k = atomicAdd(&pcnt, 1); plist[k] = tid; }
        __syncthreads();
        const int np = pcnt;
        if (np == 0) break;
        // re-bid pending rows in parallel across 16 waves
        for (int idx = wv; idx < np; idx += NWAVE) {
            const int i = plist[idx];
            const float* rp = C + (size_t)i * QQ;
            float rowv[SLOTS];
            #pragma unroll
            for (int k = 0; k < SLOTS; ++k) { const int c = qq + 64*k; rowv[k] = (c < QQ) ? rp[c] : 0.f; }
            double m1 = INFINITY, m2 = INFINITY; int j1 = QQ;
            #pragma unroll
            for (int k = 0; k < SLOTS; ++k) {
                const int c = qq + 64 * k;
                if (c < QQ) {
                    const double key = (double)rowv[k] - vA[c];
                    if (key < m1)      { m2 = m1; m1 = key; j1 = c; }
                    else if (key < m2) { m2 = key; }
                }
            }
            #pragma unroll
            for (int off = 32; off > 0; off >>= 1) {
                const double om1 = __shfl_xor(m1, off);
                const int    oj1 = __shfl_xor(j1, off);
                const double om2 = __shfl_xor(m2, off);
                if (om1 < m1 || (om1 == m1 && oj1 < j1)) {
                    m2 = fmin(m1, om2); m1 = om1; j1 = oj1;
                } else {
                    m2 = fmin(om1, m2);
                }
            }
            if (qq == 0) {
                bidm1[i] = m1; bidm2[i] = m2; bidj[i] = j1;
                bidver[i] = verA[j1];
                u[i] = m1;                   // feasible forever (v only dec.)
            }
        }
        __syncthreads();
    }

    if (wv != 0) return;   // ============ wave 0 only below; no barriers ====
    const int lane = qq;

    // collect drained rows (uniform control flow)
    int nd = 0;
    for (int i = 0; i < NT; ++i) {
        if (!assigned[i]) { if (lane == 0) djkA[nd] = i; ++nd; }
    }

    // load duals/assignment into registers
    double v_[SLOTS], minv_[SLOTS];
    int p_[SLOTS];
    #pragma unroll
    for (int k = 0; k < SLOTS; ++k) {
        const int c = lane + 64 * k;
        v_[k] = (c < QQ) ? vA[c] : 0.0;
        p_[k] = (c < QQ) ? pA[c] : -1;
    }

    // ================= Phase C: Dijkstra SAP (exact, verified R2-R7) =======
    float rowv[SLOTS];
    for (int ii = 0; ii < nd; ++ii) {
        const int i = djkA[ii];
        #pragma unroll
        for (int k = 0; k < SLOTS; ++k) minv_[k] = INFINITY;
        unsigned usedm = 0;
        int j0 = -1;
        double ui0 = u[i];
        {
            const float* rp = C + (size_t)i * QQ;
            #pragma unroll
            for (int k = 0; k < SLOTS; ++k) { const int c = lane + 64*k; rowv[k] = (c < QQ) ? rp[c] : 0.f; }
        }
        int j1, i1;

        for (;;) {
            if (j0 >= 0 && (j0 & 63) == lane) usedm |= 1u << (j0 >> 6);

            double bestv = INFINITY; int bestc = QQ;
            #pragma unroll
            for (int k = 0; k < SLOTS; ++k) {
                const int c = lane + 64 * k;
                if (c < QQ && !((usedm >> k) & 1u)) {
                    const double cur = ((double)rowv[k] - ui0) - v_[k];
                    if (cur < minv_[k]) { minv_[k] = cur; wayA[c] = j0; }
                    if (minv_[k] < bestv) { bestv = minv_[k]; bestc = c; }
                }
            }
            #pragma unroll
            for (int off = 32; off > 0; off >>= 1) {
                const double ov = __shfl_xor(bestv, off);
                const int    oc = __shfl_xor(bestc, off);
                if (ov < bestv || (ov == bestv && oc < bestc)) { bestv = ov; bestc = oc; }
            }
            const double delta = bestv;
            j1 = bestc;

            {   // i1 = p[j1] via register select + shuffle
                const int slot = j1 >> 6, lj = j1 & 63;
                int myp = p_[0];
                #pragma unroll
                for (int k = 1; k < SLOTS; ++k) if (slot == k) myp = p_[k];
                i1 = __shfl(myp, lj);
            }

            double ui_next = 0.0;
            float rown[SLOTS];
            if (i1 >= 0) {      // prefetch next row (not in tree -> u stable)
                ui_next = u[i1];
                const float* rp = C + (size_t)i1 * QQ;
                #pragma unroll
                for (int k = 0; k < SLOTS; ++k) { const int c = lane + 64*k; rown[k] = (c < QQ) ? rp[c] : 0.f; }
            }

            #pragma unroll
            for (int k = 0; k < SLOTS; ++k) {
                const int c = lane + 64 * k;
                if (c < QQ) {
                    if ((usedm >> k) & 1u) { v_[k] -= delta; u[p_[k]] += delta; }
                    else                     minv_[k] -= delta;
                }
            }
            if (lane == 0) u[i] += delta;

            j0 = j1;
            if (i1 < 0) break;
            ui0 = ui_next;
            #pragma unroll
            for (int k = 0; k < SLOTS; ++k) rowv[k] = rown[k];
        }

        if (lane == 0) {        // augment along way chain
            int jj = j1;
            while (jj >= 0) {
                const int pr = wayA[jj];
                pA[jj] = (pr < 0) ? i : pA[pr];
                jj = pr;
            }
        }
        #pragma unroll
        for (int k = 0; k < SLOTS; ++k) {
            const int c = lane + 64 * k;
            p_[k] = (c < QQ) ? pA[c] : -1;
        }
    }

    // ---- emit in increasing query order (== reference's stable argsort) ----
    #pragma unroll
    for (int k = 0; k < SLOTS; ++k) {
        const int c = lane + 64 * k;
        if (c < QQ) { const int t = pA[c]; if (t >= 0) c4r[t] = c; }
    }
    for (int t = lane; t < NT; t += 64) {
        const int c = c4r[t];
        int rank = 0;
        for (int t2 = 0; t2 < NT; ++t2) rank += (c4r[t2] < c) ? 1 : 0;
        rows_out[b * NT + rank] = c;
        cols_out[b * NT + rank] = t;
    }
}

extern "C" void kernel_launch(void* const* d_in, const int* in_sizes, int n_in,
                              void* d_out, int out_size, void* d_ws, size_t ws_size,
                              hipStream_t stream) {
    (void)in_sizes; (void)n_in; (void)out_size; (void)ws_size;
    const float* logits  = (const float*)d_in[0];
    const float* pboxes  = (const float*)d_in[1];
    const int*   tlabels = (const int*)d_in[2];
    const float* tboxes  = (const float*)d_in[3];
    float* cost = (float*)d_ws;               // (B,NT,QQ) f32 = 12.3 MB
    int*   out  = (int*)d_out;

    matcher_kernel<<<dim3(BB), 1024, 0, stream>>>(
        logits, pboxes, tlabels, tboxes, cost, out, out + BB * NT);
}